// Round 14
// baseline (154.725 us; speedup 1.0000x reference)
//
#include <hip/hip_runtime.h>

typedef short s16x8 __attribute__((ext_vector_type(8)));
typedef float f32x4 __attribute__((ext_vector_type(4)));
typedef unsigned int u32x4 __attribute__((ext_vector_type(4)));

__device__ __forceinline__ unsigned short bf16r(float f) {
  unsigned int u = __float_as_uint(f);
  u += 0x7fffu + ((u >> 16) & 1u);
  return (unsigned short)(u >> 16);
}
__device__ __forceinline__ float bf_lo(unsigned int u) {
  return __uint_as_float(u << 16);
}
__device__ __forceinline__ float bf_hi(unsigned int u) {
  return __uint_as_float(u & 0xffff0000u);
}

// ============================================================================
//                    FAST PATH  (round-6 config + poolprep v3)
// ============================================================================

// ---- poolprep3: fused max-pool + x -> padded NHWC bf16, 2x TLP ------------
// grid: 128 g * 5 band * 4 chq = 2560 blocks, 256 threads, 16 KB LDS.
// Each block: 16 channels (chunks ch0, ch0+1) x 10 rows. x read ONCE.
__global__ __launch_bounds__(256) void poolprep3_kernel(
    const float* __restrict__ x, float* __restrict__ pooled,
    unsigned short* __restrict__ xs) {
  const int blk = blockIdx.x;
  const int g = blk / 20;
  const int rem = blk % 20;
  const int band = rem >> 2;        // 0..4, rows y in [band*10, band*10+10)
  const int chq = rem & 3;          // channel quarter: chunks ch0, ch0+1
  const int ch0 = chq * 2;
  const float* xg = x + (size_t)g * 160000;
  unsigned short* xsg = xs + (size_t)g * (52 * 52 * 64);
  __shared__ float pm2[16 * 250];   // [c_local][r][xpair]
  const int tid = threadIdx.x;

  // Phase A: transpose + bf16 + pool partials. tasks (r,xpair,chunk2)=10*25*2
  for (int task = tid; task < 500; task += 256) {
    int chunk2 = task & 1;
    int rest = task >> 1;
    int xpair = rest % 25;
    int r = rest / 25;
    int y = band * 10 + r;
    int chunk = ch0 + chunk2;
    const float* base = xg + (chunk * 8) * 2500 + y * 50 + xpair * 2;
    float2 v[8];
#pragma unroll
    for (int k = 0; k < 8; ++k) v[k] = *(const float2*)(base + k * 2500);
#pragma unroll
    for (int k = 0; k < 8; ++k)
      pm2[(chunk2 * 8 + k) * 250 + r * 25 + xpair] = fmaxf(v[k].x, v[k].y);
    uint4 a, b;
    a.x = (unsigned)bf16r(v[0].x) | ((unsigned)bf16r(v[1].x) << 16);
    a.y = (unsigned)bf16r(v[2].x) | ((unsigned)bf16r(v[3].x) << 16);
    a.z = (unsigned)bf16r(v[4].x) | ((unsigned)bf16r(v[5].x) << 16);
    a.w = (unsigned)bf16r(v[6].x) | ((unsigned)bf16r(v[7].x) << 16);
    b.x = (unsigned)bf16r(v[0].y) | ((unsigned)bf16r(v[1].y) << 16);
    b.y = (unsigned)bf16r(v[2].y) | ((unsigned)bf16r(v[3].y) << 16);
    b.z = (unsigned)bf16r(v[4].y) | ((unsigned)bf16r(v[5].y) << 16);
    b.w = (unsigned)bf16r(v[6].y) | ((unsigned)bf16r(v[7].y) << 16);
    int xx = xpair * 2;
    *(uint4*)&xsg[(((y + 1) * 52) + (xx + 1)) * 64 + chunk * 8] = a;
    *(uint4*)&xsg[(((y + 1) * 52) + (xx + 2)) * 64 + chunk * 8] = b;
  }
  // Border zeros (this block's 16 channels only)
  uint4 z4;
  z4.x = 0; z4.y = 0; z4.z = 0; z4.w = 0;
  for (int task = tid; task < 40; task += 256) {  // cols 0/51, 10 rows, 2 chunks
    int chunk2 = task & 1;
    int rest = task >> 1;
    int col = (rest & 1) ? 51 : 0;
    int r = rest >> 1;
    int y = band * 10 + r;
    *(uint4*)&xsg[(((y + 1) * 52) + col) * 64 + (ch0 + chunk2) * 8] = z4;
  }
  if (band == 0) {  // padded row 0: 52 cols * 2 chunks = 104 tasks
    for (int task = tid; task < 104; task += 256)
      *(uint4*)&xsg[(task >> 1) * 64 + (ch0 + (task & 1)) * 8] = z4;
  }
  if (band == 4) {  // padded row 51
    for (int task = tid; task < 104; task += 256)
      *(uint4*)&xsg[(51 * 52 + (task >> 1)) * 64 + (ch0 + (task & 1)) * 8] = z4;
  }
  __syncthreads();
  // Phase B: LDS-only pool reduce. tasks (c_local, ox) = 80
  if (tid < 80) {
    int c_local = tid / 5, ox = tid % 5;
    const float* pr = &pm2[c_local * 250 + ox * 5];
    float m = -1e30f;
#pragma unroll
    for (int r = 0; r < 10; ++r) {
#pragma unroll
      for (int xp = 0; xp < 5; ++xp) m = fmaxf(m, pr[r * 25 + xp]);
    }
    int c_g = chq * 16 + c_local;
    pooled[(size_t)g * 1600 + c_g * 25 + band * 5 + ox] = m;
  }
}

// ---- conv helper: one ik-half compute pass (swizzle t(c)=(c>>1)&3) --------
__device__ __forceinline__ void conv_pass2(
    const unsigned short* in_s, const unsigned short* __restrict__ wg,
    f32x4 acc[4][4], int ikk, int wave, int lane, int l15, int l4) {
#pragma unroll
  for (int dy = 0; dy < 3; ++dy) {
    const int rr = wave + dy;
#pragma unroll
    for (int dx = 0; dx < 3; ++dx) {
      const int tap = dy * 3 + dx;
      s16x8 a[4], bfr[4];
#pragma unroll
      for (int mf = 0; mf < 4; ++mf)
        a[mf] = *reinterpret_cast<const s16x8*>(
            wg + ((((tap * 2 + ikk) * 4 + mf) * 64 + lane) << 3));
#pragma unroll
      for (int nf = 0; nf < 4; ++nf) {
        int cc = nf * 16 + l15 + dx;
        int slot = l4 ^ ((cc >> 1) & 3);
        bfr[nf] = *reinterpret_cast<const s16x8*>(
            &in_s[((rr * 66 + cc) << 5) + (slot << 3)]);
      }
#pragma unroll
      for (int mf = 0; mf < 4; ++mf)
#pragma unroll
        for (int nf = 0; nf < 4; ++nf)
          acc[mf][nf] = __builtin_amdgcn_mfma_f32_16x16x32_bf16(
              a[mf], bfr[nf], acc[mf][nf], 0, 0, 0);
    }
  }
}

// ---- conv_main_fast2: 4-row bands, ik-split DMA staging, 25.6 KB LDS ------
__global__ __launch_bounds__(256, 4) void conv_main_fast2(
    const unsigned short* __restrict__ xs, const unsigned short* __restrict__ wt3,
    const float* __restrict__ fb_g, float* __restrict__ out) {
  const int g = blockIdx.x & 127;
  const int band = blockIdx.x >> 7;  // 0..12
  const int y0 = band * 4;
  const int tid = threadIdx.x;
  __shared__ __align__(16) unsigned short in_s[6 * 66 * 32];
  __shared__ float fb_s[64];
  if (tid < 64) fb_s[tid] = fb_g[g * 64 + tid];

  const unsigned short* xsg = xs + (size_t)g * (52 * 52 * 64);
  const unsigned short* wg = wt3 + (size_t)g * 36864;
  const int wave = tid >> 6, lane = tid & 63;
  const int l15 = lane & 15, l4 = lane >> 4;
  const int yrow = y0 + wave;

  f32x4 acc[4][4];
  f32x4 z = {0.f, 0.f, 0.f, 0.f};
#pragma unroll
  for (int mf = 0; mf < 4; ++mf)
#pragma unroll
    for (int nf = 0; nf < 4; ++nf) acc[mf][nf] = z;

  for (int task = tid; task < 1584; task += 256) {
    int slot = task & 3;
    int c = (task >> 2) % 66;
    int r = (task >> 2) / 66;
    int py = y0 + r;
    int srcSub = slot ^ ((c >> 1) & 3);
    const unsigned short* src = xsg + ((size_t)(py * 52 + c) * 64 + srcSub * 8);
    unsigned short* ldsb = in_s + (size_t)(task & ~63) * 8;
    __builtin_amdgcn_global_load_lds(
        (const __attribute__((address_space(1))) void*)src,
        (__attribute__((address_space(3))) void*)ldsb, 16, 0, 0);
  }
  __syncthreads();
  if (yrow < 50) conv_pass2(in_s, wg, acc, 0, wave, lane, l15, l4);
  __syncthreads();
  for (int task = tid; task < 1584; task += 256) {
    int slot = task & 3;
    int c = (task >> 2) % 66;
    int r = (task >> 2) / 66;
    int py = y0 + r;
    int srcSub = slot ^ ((c >> 1) & 3);
    const unsigned short* src = xsg + ((size_t)(py * 52 + c) * 64 + 32 + srcSub * 8);
    unsigned short* ldsb = in_s + (size_t)(task & ~63) * 8;
    __builtin_amdgcn_global_load_lds(
        (const __attribute__((address_space(1))) void*)src,
        (__attribute__((address_space(3))) void*)ldsb, 16, 0, 0);
  }
  __syncthreads();
  if (yrow < 50) {
    conv_pass2(in_s, wg, acc, 1, wave, lane, l15, l4);
    float* og = out + (size_t)g * 64 * 2500 + yrow * 50;
#pragma unroll
    for (int mf = 0; mf < 4; ++mf) {
#pragma unroll
      for (int r = 0; r < 4; ++r) {
        int o = mf * 16 + l4 * 4 + r;
        float fbv = fb_s[o];
#pragma unroll
        for (int nf = 0; nf < 4; ++nf) {
          int xx = nf * 16 + l15;
          if (xx < 50) og[(size_t)o * 2500 + xx] = acc[mf][nf][r] + fbv;
        }
      }
    }
  }
}

// ---- calwt: fused calibration + per-group scaled weight pack --------------
__global__ __launch_bounds__(256) void calwt_kernel(
    const float* __restrict__ avgg, const float* __restrict__ tconvw,
    const float* __restrict__ tconvb, const float* __restrict__ fcw,
    const float* __restrict__ fcb, const float* __restrict__ bias,
    const float* __restrict__ w, float* __restrict__ fb_g,
    unsigned short* __restrict__ wt3) {
  const int g = blockIdx.x;
  const int tid = threadIdx.x;
  __shared__ float tcw_s[64 * 65];
  __shared__ float av[64];
  __shared__ float sc[64];
  for (int idx = tid; idx < 4096; idx += 256)
    tcw_s[(idx >> 6) * 65 + (idx & 63)] = tconvw[idx];
  if (tid < 64) av[tid] = avgg[g * 64 + tid];
  __syncthreads();
  if (tid < 64) {
    int o = tid;
    float cal = tconvb[o];
#pragma unroll
    for (int c = 0; c < 64; ++c) cal += tcw_s[o * 65 + c] * av[c];
    sc[o] = 1.0f + cal;
    float part = fcw[o] * av[o];
#pragma unroll
    for (int off = 32; off; off >>= 1) part += __shfl_down(part, off);
    float fc = __shfl(part, 0) + fcb[0];
    fb_g[g * 64 + o] = bias[o] * (1.0f + fc);
  }
  __syncthreads();
  unsigned short* outg = wt3 + (size_t)g * 36864;
  for (int idx = tid; idx < 36864; idx += 256) {
    int j = idx & 7;
    int lane = (idx >> 3) & 63;
    int mf = (idx >> 9) & 3;
    int ik = (idx >> 11) & 1;
    int tap = idx >> 12;
    int o = mf * 16 + (lane & 15);
    int i = ik * 32 + 8 * (lane >> 4) + j;
    outg[idx] = bf16r(w[((o * 64) + i) * 9 + tap] * sc[i]);
  }
}

// ============================================================================
//              convB v2: emits scan-ready layouts (bf16 V, kk4, p28)
// ============================================================================

__device__ __forceinline__ void conv64core(const float* pool_s,
                                           const float* __restrict__ wgt,
                                           float* red, int tid) {
  int co = tid & 63, qd = tid >> 6;
  float acc[25];
#pragma unroll
  for (int n = 0; n < 25; ++n) acc[n] = 0.f;
  for (int ci = qd * 16; ci < qd * 16 + 16; ++ci) {
    float in[25];
#pragma unroll
    for (int n = 0; n < 25; ++n) in[n] = pool_s[ci * 25 + n];
    float w9[9];
#pragma unroll
    for (int tp = 0; tp < 9; ++tp) w9[tp] = wgt[(co * 64 + ci) * 9 + tp];
#pragma unroll
    for (int n = 0; n < 25; ++n) {
      int y = n / 5, xx = n % 5;
#pragma unroll
      for (int dy = 0; dy < 3; ++dy) {
        int yy = y + dy - 1;
        if (yy < 0 || yy > 4) continue;
#pragma unroll
        for (int dx = 0; dx < 3; ++dx) {
          int xc = xx + dx - 1;
          if (xc < 0 || xc > 4) continue;
          acc[n] += in[yy * 5 + xc] * w9[dy * 3 + dx];
        }
      }
    }
  }
#pragma unroll
  for (int n = 0; n < 25; ++n) red[(qd * 64 + co) * 25 + n] = acc[n];
  __syncthreads();
}

__global__ __launch_bounds__(256) void convB2_kernel(
    const float* __restrict__ pooled, const float* __restrict__ vw,
    const float* __restrict__ vb, const float* __restrict__ kw,
    const float* __restrict__ kb, const float* __restrict__ iw,
    const float* __restrict__ ib, unsigned short* __restrict__ vbg,
    float* __restrict__ kk4g, float* __restrict__ p28g) {
  const int blk = blockIdx.x;
  __shared__ float pool_s[1600];
  __shared__ float red[6400];
  const int tid = threadIdx.x;
  for (int idx = tid; idx < 1600; idx += 256) pool_s[idx] = pooled[blk * 1600 + idx];
  __syncthreads();

  conv64core(pool_s, vw, red, tid);
  {
    unsigned short* dst = vbg + (size_t)blk * 2560;
    for (int idx = tid; idx < 1600; idx += 256) {
      float s = red[idx] + red[1600 + idx] + red[3200 + idx] + red[4800 + idx];
      dst[(idx / 25) * 40 + idx % 25] = bf16r(s + vb[idx / 25]);
    }
    for (int idx = tid; idx < 960; idx += 256)
      dst[(idx / 15) * 40 + 25 + idx % 15] = 0;
  }
  __syncthreads();

  {
    int co = tid & 3, ci = tid >> 2;
    float acc[25];
#pragma unroll
    for (int n = 0; n < 25; ++n) acc[n] = 0.f;
    float in[25];
#pragma unroll
    for (int n = 0; n < 25; ++n) in[n] = pool_s[ci * 25 + n];
    float w9[9];
#pragma unroll
    for (int tp = 0; tp < 9; ++tp) w9[tp] = kw[(co * 64 + ci) * 9 + tp];
#pragma unroll
    for (int n = 0; n < 25; ++n) {
      int y = n / 5, xx = n % 5;
#pragma unroll
      for (int dy = 0; dy < 3; ++dy) {
        int yy = y + dy - 1;
        if (yy < 0 || yy > 4) continue;
#pragma unroll
        for (int dx = 0; dx < 3; ++dx) {
          int xc = xx + dx - 1;
          if (xc < 0 || xc > 4) continue;
          acc[n] += in[yy * 5 + xc] * w9[dy * 3 + dx];
        }
      }
    }
#pragma unroll
    for (int n = 0; n < 25; ++n) red[(ci * 4 + co) * 25 + n] = acc[n];
  }
  __syncthreads();
  if (tid < 100) {
    int co = tid / 25, m = tid % 25;
    float s = 0.f;
    for (int c = 0; c < 64; ++c) s += red[(c * 4 + co) * 25 + m];
    kk4g[blk * 100 + m * 4 + co] = s + kb[co];
  }
  __syncthreads();

  if ((blk & 7) == 0) {
    conv64core(pool_s, iw, red, tid);
    float* dst = p28g + (size_t)(blk >> 3) * 1792;
    for (int idx = tid; idx < 1600; idx += 256) {
      float s = red[idx] + red[1600 + idx] + red[3200 + idx] + red[4800 + idx];
      dst[(idx / 25) * 28 + idx % 25] = s + ib[idx / 25];
    }
  }
}

// ============================================================================
//                 scan v3 (round-6): bf16 V/attn, vectorized LDS
// ============================================================================

__global__ __launch_bounds__(256) void scan3_kernel(
    const unsigned short* __restrict__ vbg, const float* __restrict__ kk4g,
    const float* __restrict__ p28g, const float* __restrict__ qw,
    const float* __restrict__ qb, float* __restrict__ avgg) {
  const int b = blockIdx.x;
  const int tid = threadIdx.x;
  __shared__ __align__(16) unsigned short v_bf[8 * 64 * 40];
  __shared__ __align__(16) unsigned short attn_bf[25 * 32];
  __shared__ float p_s[64 * 28];
  __shared__ float red[100 * 68];
  __shared__ f32x4 kk4_s[8 * 25];
  __shared__ float q_s[100];
  __shared__ float qw_s[2304];
  __shared__ float avgp[256];
  __shared__ float qb_s[4];

  {
    const u32x4* vs = (const u32x4*)(vbg + (size_t)b * 20480);
    u32x4* vd = (u32x4*)v_bf;
    for (int i = tid; i < 2560; i += 256) vd[i] = vs[i];
    const f32x4* ks = (const f32x4*)(kk4g + b * 800);
    for (int i = tid; i < 200; i += 256) kk4_s[i] = ks[i];
    const f32x4* ps = (const f32x4*)(p28g + (size_t)b * 1792);
    f32x4* pd = (f32x4*)p_s;
    for (int i = tid; i < 448; i += 256) pd[i] = ps[i];
    const f32x4* qs = (const f32x4*)qw;
    f32x4* qd = (f32x4*)qw_s;
    for (int i = tid; i < 576; i += 256) qd[i] = qs[i];
    if (tid < 4) qb_s[tid] = qb[tid];
  }
  __syncthreads();

  const int qco = tid & 3, qci = tid >> 2;
  float qwr[9];
#pragma unroll
  for (int tp = 0; tp < 9; ++tp) qwr[tp] = qw_s[(qco * 64 + qci) * 9 + tp];

#pragma unroll 1
  for (int l = 0; l < 8; ++l) {
    {
      f32x4 i4[7];
      const f32x4* pr = (const f32x4*)&p_s[qci * 28];
#pragma unroll
      for (int j = 0; j < 7; ++j) i4[j] = pr[j];
      float in[25];
#pragma unroll
      for (int n = 0; n < 25; ++n) in[n] = i4[n >> 2][n & 3];
      float acc[25];
#pragma unroll
      for (int n = 0; n < 25; ++n) acc[n] = 0.f;
#pragma unroll
      for (int n = 0; n < 25; ++n) {
        int y = n / 5, xx = n % 5;
#pragma unroll
        for (int dy = 0; dy < 3; ++dy) {
          int yy = y + dy - 1;
          if (yy < 0 || yy > 4) continue;
#pragma unroll
          for (int dx = 0; dx < 3; ++dx) {
            int xc = xx + dx - 1;
            if (xc < 0 || xc > 4) continue;
            acc[n] += in[yy * 5 + xc] * qwr[dy * 3 + dx];
          }
        }
      }
#pragma unroll
      for (int n = 0; n < 25; ++n) red[(qco * 25 + n) * 68 + qci] = acc[n];
    }
    if (l > 0 && tid < 64) {
      f32x4 a4 = *(const f32x4*)&avgp[tid * 4];
      avgg[(b * 8 + l - 1) * 64 + tid] = (a4[0] + a4[1] + a4[2] + a4[3]) * 0.04f;
    }
    __syncthreads();

    if (tid < 200) {
      int row = tid >> 1, h = tid & 1;
      const f32x4* rp = (const f32x4*)&red[row * 68 + h * 32];
      float s = 0.f;
#pragma unroll
      for (int j = 0; j < 8; ++j) {
        f32x4 r4 = rp[j];
        s += r4[0] + r4[1] + r4[2] + r4[3];
      }
      s += __shfl_down(s, 1);
      if (h == 0) q_s[row] = s + qb_s[row / 25];
    }
    __syncthreads();

    if (tid < 25) {
      const int n = tid;
      const f32x4* kk = &kk4_s[l * 25];
      float q0 = q_s[n], q1 = q_s[25 + n], q2 = q_s[50 + n], q3 = q_s[75 + n];
      float row[25];
      float mx = -1e30f;
#pragma unroll
      for (int m = 0; m < 25; ++m) {
        f32x4 k4 = kk[m];
        float s = q0 * k4[0] + q1 * k4[1] + q2 * k4[2] + q3 * k4[3];
        row[m] = s;
        mx = fmaxf(mx, s);
      }
      float sm = 0.f;
#pragma unroll
      for (int m = 0; m < 25; ++m) {
        float e = __expf(row[m] - mx);
        row[m] = e;
        sm += e;
      }
      float inv = 1.0f / sm;
      unsigned int w16[16];
#pragma unroll
      for (int j = 0; j < 16; ++j) {
        float lo = (2 * j < 25) ? row[2 * j] * inv : 0.f;
        float hi = (2 * j + 1 < 25) ? row[2 * j + 1] * inv : 0.f;
        w16[j] = (unsigned)bf16r(lo) | ((unsigned)bf16r(hi) << 16);
      }
      u32x4* ad = (u32x4*)&attn_bf[n * 32];
      u32x4 d0 = {w16[0], w16[1], w16[2], w16[3]};
      u32x4 d1 = {w16[4], w16[5], w16[6], w16[7]};
      u32x4 d2 = {w16[8], w16[9], w16[10], w16[11]};
      u32x4 d3 = {w16[12], w16[13], w16[14], w16[15]};
      ad[0] = d0; ad[1] = d1; ad[2] = d2; ad[3] = d3;
    }
    __syncthreads();

    {
      const int c = tid & 63, grp = tid >> 6;
      const u32x4* vr = (const u32x4*)&v_bf[(l * 64 + c) * 40];
      u32x4 vv[4];
#pragma unroll
      for (int j = 0; j < 4; ++j) vv[j] = vr[j];
      float vf[25];
#pragma unroll
      for (int m = 0; m < 25; ++m) {
        unsigned int u = vv[m >> 3][(m >> 1) & 3];
        vf[m] = (m & 1) ? bf_hi(u) : bf_lo(u);
      }
      float partial = 0.f;
      for (int n = grp; n < 25; n += 4) {
        const u32x4* ar = (const u32x4*)&attn_bf[n * 32];
        u32x4 aa[4];
#pragma unroll
        for (int j = 0; j < 4; ++j) aa[j] = ar[j];
        float acc = 0.f;
#pragma unroll
        for (int m = 0; m < 25; ++m) {
          unsigned int u = aa[m >> 3][(m >> 1) & 3];
          float a = (m & 1) ? bf_hi(u) : bf_lo(u);
          acc += vf[m] * a;
        }
        p_s[c * 28 + n] = acc;
        partial += acc;
      }
      avgp[(c << 2) + grp] = partial;
    }
    __syncthreads();
  }
  if (tid < 64) {
    f32x4 a4 = *(const f32x4*)&avgp[tid * 4];
    avgg[(b * 8 + 7) * 64 + tid] = (a4[0] + a4[1] + a4[2] + a4[3]) * 0.04f;
  }
}

// ============================================================================
//                       LEGACY PATH — fallback only
// ============================================================================

__global__ __launch_bounds__(256) void pool_kernel(const float* __restrict__ x,
                                                   float* __restrict__ pooled) {
  const int blk = blockIdx.x;
  const float* plane = x + (size_t)blk * 2500;
  __shared__ float pmax[250];
  const int t = threadIdx.x;
  if (t < 250) {
    int r = t / 5, cc = t % 5;
    const float* row = plane + r * 50 + cc * 10;
    float m = row[0];
#pragma unroll
    for (int j = 1; j < 10; ++j) m = fmaxf(m, row[j]);
    pmax[r * 5 + cc] = m;
  }
  __syncthreads();
  if (t < 25) {
    int pr = t / 5, cc = t % 5;
    float m = pmax[(pr * 10) * 5 + cc];
#pragma unroll
    for (int rr = 1; rr < 10; ++rr) m = fmaxf(m, pmax[(pr * 10 + rr) * 5 + cc]);
    pooled[(size_t)blk * 25 + t] = m;
  }
}

__global__ __launch_bounds__(256) void wt_kernel(const float* __restrict__ w,
                                                 unsigned short* __restrict__ wt2) {
  int idx = blockIdx.x * 256 + threadIdx.x;
  if (idx >= 36864) return;
  int j = idx & 7;
  int lane = (idx >> 3) & 63;
  int mf = (idx >> 9) & 3;
  int ik = (idx >> 11) & 1;
  int tap = idx >> 12;
  int o = mf * 16 + (lane & 15);
  int i = ik * 32 + 8 * (lane >> 4) + j;
  wt2[idx] = bf16r(w[((o * 64) + i) * 9 + tap]);
}

__global__ __launch_bounds__(256) void conv_main(
    const float* __restrict__ x, const unsigned short* __restrict__ wt2,
    const float* __restrict__ scale_g, const float* __restrict__ fb_g,
    float* __restrict__ out) {
  const int g = blockIdx.x & 127;
  const int band = blockIdx.x >> 7;
  const int y0 = band * 4;
  const int tid = threadIdx.x;
  __shared__ unsigned short in_s[6 * 66 * 64];
  __shared__ float scale_s[64], fb_s[64];
  if (tid < 64) {
    scale_s[tid] = scale_g[g * 64 + tid];
    fb_s[tid] = fb_g[g * 64 + tid];
  }
  __syncthreads();
  const float* xg = x + (size_t)g * 160000;
  for (int task = tid; task < 3168; task += 256) {
    int c = task % 66;
    int rc = task / 66;
    int r = rc >> 3;
    int chunk = rc & 7;
    int y = y0 - 1 + r;
    int xi = c - 1;
    unsigned int p0 = 0, p1 = 0, p2 = 0, p3 = 0;
    if (y >= 0 && y < 50 && xi >= 0 && xi < 50) {
      const float* px = xg + chunk * 8 * 2500 + y * 50 + xi;
      float f0 = px[0] * scale_s[chunk * 8 + 0];
      float f1 = px[2500] * scale_s[chunk * 8 + 1];
      float f2 = px[5000] * scale_s[chunk * 8 + 2];
      float f3 = px[7500] * scale_s[chunk * 8 + 3];
      float f4 = px[10000] * scale_s[chunk * 8 + 4];
      float f5 = px[12500] * scale_s[chunk * 8 + 5];
      float f6 = px[15000] * scale_s[chunk * 8 + 6];
      float f7 = px[17500] * scale_s[chunk * 8 + 7];
      p0 = (unsigned)bf16r(f0) | ((unsigned)bf16r(f1) << 16);
      p1 = (unsigned)bf16r(f2) | ((unsigned)bf16r(f3) << 16);
      p2 = (unsigned)bf16r(f4) | ((unsigned)bf16r(f5) << 16);
      p3 = (unsigned)bf16r(f6) | ((unsigned)bf16r(f7) << 16);
    }
    int chS = chunk ^ (c & 7);
    uint4* dst = (uint4*)&in_s[((r * 66 + c) << 6) + (chS << 3)];
    uint4 u4;
    u4.x = p0; u4.y = p1; u4.z = p2; u4.w = p3;
    *dst = u4;
  }
  __syncthreads();
  const int wave = tid >> 6, lane = tid & 63;
  const int l15 = lane & 15, l4 = lane >> 4;
  const int yrow = y0 + wave;
  if (yrow < 50) {
    f32x4 acc[4][4];
    f32x4 z = {0.f, 0.f, 0.f, 0.f};
#pragma unroll
    for (int mf = 0; mf < 4; ++mf)
#pragma unroll
      for (int nf = 0; nf < 4; ++nf) acc[mf][nf] = z;
#pragma unroll
    for (int dy = 0; dy < 3; ++dy) {
      const int rr = wave + dy;
#pragma unroll
      for (int dx = 0; dx < 3; ++dx) {
        const int tap = dy * 3 + dx;
#pragma unroll
        for (int ik = 0; ik < 2; ++ik) {
          s16x8 a[4], bfr[4];
#pragma unroll
          for (int mf = 0; mf < 4; ++mf)
            a[mf] = *reinterpret_cast<const s16x8*>(
                wt2 + ((((tap * 2 + ik) * 4 + mf) * 64 + lane) << 3));
#pragma unroll
          for (int nf = 0; nf < 4; ++nf) {
            int cc = nf * 16 + l15 + dx;
            int chS = (ik * 4 + l4) ^ (cc & 7);
            bfr[nf] = *reinterpret_cast<const s16x8*>(
                &in_s[((rr * 66 + cc) << 6) + (chS << 3)]);
          }
#pragma unroll
          for (int mf = 0; mf < 4; ++mf)
#pragma unroll
            for (int nf = 0; nf < 4; ++nf)
              acc[mf][nf] = __builtin_amdgcn_mfma_f32_16x16x32_bf16(
                  a[mf], bfr[nf], acc[mf][nf], 0, 0, 0);
        }
      }
    }
    float* og = out + (size_t)g * 64 * 2500 + yrow * 50;
#pragma unroll
    for (int mf = 0; mf < 4; ++mf) {
#pragma unroll
      for (int r = 0; r < 4; ++r) {
        int o = mf * 16 + l4 * 4 + r;
        float fbv = fb_s[o];
#pragma unroll
        for (int nf = 0; nf < 4; ++nf) {
          int xx = nf * 16 + l15;
          if (xx < 50) og[(size_t)o * 2500 + xx] = acc[mf][nf][r] + fbv;
        }
      }
    }
  }
}

__global__ __launch_bounds__(256) void calib_kernel(
    const float* __restrict__ avgg, const float* __restrict__ tconvw,
    const float* __restrict__ tconvb, const float* __restrict__ fcw,
    const float* __restrict__ fcb, const float* __restrict__ bias,
    float* __restrict__ scale_g, float* __restrict__ fb_g) {
  const int tid = threadIdx.x;
  const int wave = tid >> 6, o = tid & 63;
  const int bl = blockIdx.x * 4 + wave;
  __shared__ float tcw_s[64 * 65];
  __shared__ float avgl[4][64];
  for (int idx = tid; idx < 4096; idx += 256)
    tcw_s[(idx >> 6) * 65 + (idx & 63)] = tconvw[idx];
  avgl[wave][o] = avgg[bl * 64 + o];
  __syncthreads();
  float cal = tconvb[o];
  const float* av = avgl[wave];
#pragma unroll
  for (int c = 0; c < 64; ++c) cal += tcw_s[o * 65 + c] * av[c];
  scale_g[bl * 64 + o] = 1.0f + cal;
  float part = fcw[o] * av[o];
#pragma unroll
  for (int off = 32; off; off >>= 1) part += __shfl_down(part, off);
  float fc = __shfl(part, 0) + fcb[0];
  fb_g[bl * 64 + o] = bias[o] * (1.0f + fc);
}

// --------------------------------- launch ---------------------------------
extern "C" void kernel_launch(void* const* d_in, const int* in_sizes, int n_in,
                              void* d_out, int out_size, void* d_ws, size_t ws_size,
                              hipStream_t stream) {
  const float* x       = (const float*)d_in[0];
  const float* weight  = (const float*)d_in[1];
  const float* bias    = (const float*)d_in[2];
  const float* init_w  = (const float*)d_in[3];
  const float* init_b  = (const float*)d_in[4];
  const float* q_w     = (const float*)d_in[5];
  const float* q_b     = (const float*)d_in[6];
  const float* k_w     = (const float*)d_in[7];
  const float* k_b     = (const float*)d_in[8];
  const float* v_w     = (const float*)d_in[9];
  const float* v_b     = (const float*)d_in[10];
  const float* tconv_w = (const float*)d_in[11];
  const float* tconv_b = (const float*)d_in[12];
  const float* fc_w    = (const float*)d_in[13];
  const float* fc_b    = (const float*)d_in[14];
  float* out = (float*)d_out;

  float* ws = (float*)d_ws;
  float* pooled = ws;                                      // 204800 f
  unsigned short* vbg = (unsigned short*)(ws + 204800);    // 327680 us
  float* kk4g   = ws + 368640;                             // 12800 f
  float* p28g   = ws + 381440;                             // 28672 f
  float* scaleg = ws + 410112;                             // 8192 f (legacy)
  float* fbg    = ws + 418304;                             // 8192 f
  float* avgg   = ws + 426496;                             // 8192 f
  unsigned short* wt3 = (unsigned short*)(ws + 434688);    // 4718592 us
  unsigned short* xsb = wt3 + 4718592;                     // 22151168 us

  const size_t NEED_FAST = 55543808ull;

  if (ws_size >= NEED_FAST) {
    poolprep3_kernel<<<2560, 256, 0, stream>>>(x, pooled, xsb);
    convB2_kernel<<<128, 256, 0, stream>>>(pooled, v_w, v_b, k_w, k_b, init_w,
                                           init_b, vbg, kk4g, p28g);
    scan3_kernel<<<16, 256, 0, stream>>>(vbg, kk4g, p28g, q_w, q_b, avgg);
    calwt_kernel<<<128, 256, 0, stream>>>(avgg, tconv_w, tconv_b, fc_w, fc_b, bias,
                                          weight, fbg, wt3);
    conv_main_fast2<<<13 * 128, 256, 0, stream>>>(xsb, wt3, fbg, out);
  } else {
    unsigned short* wt2 = (unsigned short*)(ws + 434688);
    pool_kernel<<<8192, 256, 0, stream>>>(x, pooled);
    wt_kernel<<<144, 256, 0, stream>>>(weight, wt2);
    convB2_kernel<<<128, 256, 0, stream>>>(pooled, v_w, v_b, k_w, k_b, init_w,
                                           init_b, vbg, kk4g, p28g);
    scan3_kernel<<<16, 256, 0, stream>>>(vbg, kk4g, p28g, q_w, q_b, avgg);
    calib_kernel<<<32, 256, 0, stream>>>(avgg, tconv_w, tconv_b, fc_w, fc_b, bias,
                                         scaleg, fbg);
    conv_main<<<13 * 128, 256, 0, stream>>>(x, wt2, scaleg, fbg, out);
  }
}

// Round 15
// 149.303 us; speedup vs baseline: 1.0363x; 1.0363x over previous
//
#include <hip/hip_runtime.h>

typedef short s16x8 __attribute__((ext_vector_type(8)));
typedef float f32x4 __attribute__((ext_vector_type(4)));
typedef unsigned int u32x4 __attribute__((ext_vector_type(4)));

__device__ __forceinline__ unsigned short bf16r(float f) {
  unsigned int u = __float_as_uint(f);
  u += 0x7fffu + ((u >> 16) & 1u);
  return (unsigned short)(u >> 16);
}
__device__ __forceinline__ float bf_lo(unsigned int u) {
  return __uint_as_float(u << 16);
}
__device__ __forceinline__ float bf_hi(unsigned int u) {
  return __uint_as_float(u & 0xffff0000u);
}

// ============================================================================
//                    FAST PATH  (round-6/13 verified best config)
// ============================================================================

// ---- poolprep2: fused max-pool + x -> padded NHWC bf16 (x read ONCE) ------
__global__ __launch_bounds__(256) void poolprep2_kernel(
    const float* __restrict__ x, float* __restrict__ pooled,
    unsigned short* __restrict__ xs) {
  const int blk = blockIdx.x;
  const int g = blk / 10;
  const int rem = blk % 10;
  const int band = rem >> 1;
  const int chalf = rem & 1;
  const int ch0 = chalf * 4;
  const float* xg = x + (size_t)g * 160000;
  unsigned short* xsg = xs + (size_t)g * (52 * 52 * 64);
  __shared__ float pm2[32 * 250];
  const int tid = threadIdx.x;

  for (int task = tid; task < 1000; task += 256) {
    int chunk4 = task & 3;
    int rest = task >> 2;
    int xpair = rest % 25;
    int r = rest / 25;
    int y = band * 10 + r;
    int chunk = ch0 + chunk4;
    const float* base = xg + (chunk * 8) * 2500 + y * 50 + xpair * 2;
    float2 v[8];
#pragma unroll
    for (int k = 0; k < 8; ++k) v[k] = *(const float2*)(base + k * 2500);
#pragma unroll
    for (int k = 0; k < 8; ++k)
      pm2[(chunk4 * 8 + k) * 250 + r * 25 + xpair] = fmaxf(v[k].x, v[k].y);
    uint4 a, b;
    a.x = (unsigned)bf16r(v[0].x) | ((unsigned)bf16r(v[1].x) << 16);
    a.y = (unsigned)bf16r(v[2].x) | ((unsigned)bf16r(v[3].x) << 16);
    a.z = (unsigned)bf16r(v[4].x) | ((unsigned)bf16r(v[5].x) << 16);
    a.w = (unsigned)bf16r(v[6].x) | ((unsigned)bf16r(v[7].x) << 16);
    b.x = (unsigned)bf16r(v[0].y) | ((unsigned)bf16r(v[1].y) << 16);
    b.y = (unsigned)bf16r(v[2].y) | ((unsigned)bf16r(v[3].y) << 16);
    b.z = (unsigned)bf16r(v[4].y) | ((unsigned)bf16r(v[5].y) << 16);
    b.w = (unsigned)bf16r(v[6].y) | ((unsigned)bf16r(v[7].y) << 16);
    int xx = xpair * 2;
    *(uint4*)&xsg[(((y + 1) * 52) + (xx + 1)) * 64 + chunk * 8] = a;
    *(uint4*)&xsg[(((y + 1) * 52) + (xx + 2)) * 64 + chunk * 8] = b;
  }
  uint4 z4;
  z4.x = 0; z4.y = 0; z4.z = 0; z4.w = 0;
  for (int task = tid; task < 80; task += 256) {
    int chunk4 = task & 3;
    int rest = task >> 2;
    int col = (rest & 1) ? 51 : 0;
    int r = rest >> 1;
    int y = band * 10 + r;
    *(uint4*)&xsg[(((y + 1) * 52) + col) * 64 + (ch0 + chunk4) * 8] = z4;
  }
  if (band == 0) {
    for (int task = tid; task < 208; task += 256)
      *(uint4*)&xsg[(task >> 2) * 64 + (ch0 + (task & 3)) * 8] = z4;
  }
  if (band == 4) {
    for (int task = tid; task < 208; task += 256)
      *(uint4*)&xsg[(51 * 52 + (task >> 2)) * 64 + (ch0 + (task & 3)) * 8] = z4;
  }
  __syncthreads();
  if (tid < 160) {
    int c_local = tid / 5, ox = tid % 5;
    const float* pr = &pm2[c_local * 250 + ox * 5];
    float m = -1e30f;
#pragma unroll
    for (int r = 0; r < 10; ++r) {
#pragma unroll
      for (int xp = 0; xp < 5; ++xp) m = fmaxf(m, pr[r * 25 + xp]);
    }
    int c_g = chalf * 32 + c_local;
    pooled[(size_t)g * 1600 + c_g * 25 + band * 5 + ox] = m;
  }
}

// ---- conv helper: one ik-half compute pass (swizzle t(c)=(c>>1)&3) --------
__device__ __forceinline__ void conv_pass2(
    const unsigned short* in_s, const unsigned short* __restrict__ wg,
    f32x4 acc[4][4], int ikk, int wave, int lane, int l15, int l4) {
#pragma unroll
  for (int dy = 0; dy < 3; ++dy) {
    const int rr = wave + dy;
#pragma unroll
    for (int dx = 0; dx < 3; ++dx) {
      const int tap = dy * 3 + dx;
      s16x8 a[4], bfr[4];
#pragma unroll
      for (int mf = 0; mf < 4; ++mf)
        a[mf] = *reinterpret_cast<const s16x8*>(
            wg + ((((tap * 2 + ikk) * 4 + mf) * 64 + lane) << 3));
#pragma unroll
      for (int nf = 0; nf < 4; ++nf) {
        int cc = nf * 16 + l15 + dx;
        int slot = l4 ^ ((cc >> 1) & 3);
        bfr[nf] = *reinterpret_cast<const s16x8*>(
            &in_s[((rr * 66 + cc) << 5) + (slot << 3)]);
      }
#pragma unroll
      for (int mf = 0; mf < 4; ++mf)
#pragma unroll
        for (int nf = 0; nf < 4; ++nf)
          acc[mf][nf] = __builtin_amdgcn_mfma_f32_16x16x32_bf16(
              a[mf], bfr[nf], acc[mf][nf], 0, 0, 0);
    }
  }
}

// ---- conv_main_fast2: 4-row bands, ik-split DMA staging, 25.6 KB LDS ------
__global__ __launch_bounds__(256, 4) void conv_main_fast2(
    const unsigned short* __restrict__ xs, const unsigned short* __restrict__ wt3,
    const float* __restrict__ fb_g, float* __restrict__ out) {
  const int g = blockIdx.x & 127;
  const int band = blockIdx.x >> 7;  // 0..12
  const int y0 = band * 4;
  const int tid = threadIdx.x;
  __shared__ __align__(16) unsigned short in_s[6 * 66 * 32];
  __shared__ float fb_s[64];
  if (tid < 64) fb_s[tid] = fb_g[g * 64 + tid];

  const unsigned short* xsg = xs + (size_t)g * (52 * 52 * 64);
  const unsigned short* wg = wt3 + (size_t)g * 36864;
  const int wave = tid >> 6, lane = tid & 63;
  const int l15 = lane & 15, l4 = lane >> 4;
  const int yrow = y0 + wave;

  f32x4 acc[4][4];
  f32x4 z = {0.f, 0.f, 0.f, 0.f};
#pragma unroll
  for (int mf = 0; mf < 4; ++mf)
#pragma unroll
    for (int nf = 0; nf < 4; ++nf) acc[mf][nf] = z;

  for (int task = tid; task < 1584; task += 256) {
    int slot = task & 3;
    int c = (task >> 2) % 66;
    int r = (task >> 2) / 66;
    int py = y0 + r;
    int srcSub = slot ^ ((c >> 1) & 3);
    const unsigned short* src = xsg + ((size_t)(py * 52 + c) * 64 + srcSub * 8);
    unsigned short* ldsb = in_s + (size_t)(task & ~63) * 8;
    __builtin_amdgcn_global_load_lds(
        (const __attribute__((address_space(1))) void*)src,
        (__attribute__((address_space(3))) void*)ldsb, 16, 0, 0);
  }
  __syncthreads();
  if (yrow < 50) conv_pass2(in_s, wg, acc, 0, wave, lane, l15, l4);
  __syncthreads();
  for (int task = tid; task < 1584; task += 256) {
    int slot = task & 3;
    int c = (task >> 2) % 66;
    int r = (task >> 2) / 66;
    int py = y0 + r;
    int srcSub = slot ^ ((c >> 1) & 3);
    const unsigned short* src = xsg + ((size_t)(py * 52 + c) * 64 + 32 + srcSub * 8);
    unsigned short* ldsb = in_s + (size_t)(task & ~63) * 8;
    __builtin_amdgcn_global_load_lds(
        (const __attribute__((address_space(1))) void*)src,
        (__attribute__((address_space(3))) void*)ldsb, 16, 0, 0);
  }
  __syncthreads();
  if (yrow < 50) {
    conv_pass2(in_s, wg, acc, 1, wave, lane, l15, l4);
    float* og = out + (size_t)g * 64 * 2500 + yrow * 50;
#pragma unroll
    for (int mf = 0; mf < 4; ++mf) {
#pragma unroll
      for (int r = 0; r < 4; ++r) {
        int o = mf * 16 + l4 * 4 + r;
        float fbv = fb_s[o];
#pragma unroll
        for (int nf = 0; nf < 4; ++nf) {
          int xx = nf * 16 + l15;
          if (xx < 50) og[(size_t)o * 2500 + xx] = acc[mf][nf][r] + fbv;
        }
      }
    }
  }
}

// ---- calwt: fused calibration + per-group scaled weight pack --------------
__global__ __launch_bounds__(256) void calwt_kernel(
    const float* __restrict__ avgg, const float* __restrict__ tconvw,
    const float* __restrict__ tconvb, const float* __restrict__ fcw,
    const float* __restrict__ fcb, const float* __restrict__ bias,
    const float* __restrict__ w, float* __restrict__ fb_g,
    unsigned short* __restrict__ wt3) {
  const int g = blockIdx.x;
  const int tid = threadIdx.x;
  __shared__ float tcw_s[64 * 65];
  __shared__ float av[64];
  __shared__ float sc[64];
  for (int idx = tid; idx < 4096; idx += 256)
    tcw_s[(idx >> 6) * 65 + (idx & 63)] = tconvw[idx];
  if (tid < 64) av[tid] = avgg[g * 64 + tid];
  __syncthreads();
  if (tid < 64) {
    int o = tid;
    float cal = tconvb[o];
#pragma unroll
    for (int c = 0; c < 64; ++c) cal += tcw_s[o * 65 + c] * av[c];
    sc[o] = 1.0f + cal;
    float part = fcw[o] * av[o];
#pragma unroll
    for (int off = 32; off; off >>= 1) part += __shfl_down(part, off);
    float fc = __shfl(part, 0) + fcb[0];
    fb_g[g * 64 + o] = bias[o] * (1.0f + fc);
  }
  __syncthreads();
  unsigned short* outg = wt3 + (size_t)g * 36864;
  for (int idx = tid; idx < 36864; idx += 256) {
    int j = idx & 7;
    int lane = (idx >> 3) & 63;
    int mf = (idx >> 9) & 3;
    int ik = (idx >> 11) & 1;
    int tap = idx >> 12;
    int o = mf * 16 + (lane & 15);
    int i = ik * 32 + 8 * (lane >> 4) + j;
    outg[idx] = bf16r(w[((o * 64) + i) * 9 + tap] * sc[i]);
  }
}

// ============================================================================
//              convB v2: emits scan-ready layouts (bf16 V, kk4, p28)
// ============================================================================

__device__ __forceinline__ void conv64core(const float* pool_s,
                                           const float* __restrict__ wgt,
                                           float* red, int tid) {
  int co = tid & 63, qd = tid >> 6;
  float acc[25];
#pragma unroll
  for (int n = 0; n < 25; ++n) acc[n] = 0.f;
  for (int ci = qd * 16; ci < qd * 16 + 16; ++ci) {
    float in[25];
#pragma unroll
    for (int n = 0; n < 25; ++n) in[n] = pool_s[ci * 25 + n];
    float w9[9];
#pragma unroll
    for (int tp = 0; tp < 9; ++tp) w9[tp] = wgt[(co * 64 + ci) * 9 + tp];
#pragma unroll
    for (int n = 0; n < 25; ++n) {
      int y = n / 5, xx = n % 5;
#pragma unroll
      for (int dy = 0; dy < 3; ++dy) {
        int yy = y + dy - 1;
        if (yy < 0 || yy > 4) continue;
#pragma unroll
        for (int dx = 0; dx < 3; ++dx) {
          int xc = xx + dx - 1;
          if (xc < 0 || xc > 4) continue;
          acc[n] += in[yy * 5 + xc] * w9[dy * 3 + dx];
        }
      }
    }
  }
#pragma unroll
  for (int n = 0; n < 25; ++n) red[(qd * 64 + co) * 25 + n] = acc[n];
  __syncthreads();
}

__global__ __launch_bounds__(256) void convB2_kernel(
    const float* __restrict__ pooled, const float* __restrict__ vw,
    const float* __restrict__ vb, const float* __restrict__ kw,
    const float* __restrict__ kb, const float* __restrict__ iw,
    const float* __restrict__ ib, unsigned short* __restrict__ vbg,
    float* __restrict__ kk4g, float* __restrict__ p28g) {
  const int blk = blockIdx.x;
  __shared__ float pool_s[1600];
  __shared__ float red[6400];
  const int tid = threadIdx.x;
  for (int idx = tid; idx < 1600; idx += 256) pool_s[idx] = pooled[blk * 1600 + idx];
  __syncthreads();

  conv64core(pool_s, vw, red, tid);
  {
    unsigned short* dst = vbg + (size_t)blk * 2560;
    for (int idx = tid; idx < 1600; idx += 256) {
      float s = red[idx] + red[1600 + idx] + red[3200 + idx] + red[4800 + idx];
      dst[(idx / 25) * 40 + idx % 25] = bf16r(s + vb[idx / 25]);
    }
    for (int idx = tid; idx < 960; idx += 256)
      dst[(idx / 15) * 40 + 25 + idx % 15] = 0;
  }
  __syncthreads();

  {
    int co = tid & 3, ci = tid >> 2;
    float acc[25];
#pragma unroll
    for (int n = 0; n < 25; ++n) acc[n] = 0.f;
    float in[25];
#pragma unroll
    for (int n = 0; n < 25; ++n) in[n] = pool_s[ci * 25 + n];
    float w9[9];
#pragma unroll
    for (int tp = 0; tp < 9; ++tp) w9[tp] = kw[(co * 64 + ci) * 9 + tp];
#pragma unroll
    for (int n = 0; n < 25; ++n) {
      int y = n / 5, xx = n % 5;
#pragma unroll
      for (int dy = 0; dy < 3; ++dy) {
        int yy = y + dy - 1;
        if (yy < 0 || yy > 4) continue;
#pragma unroll
        for (int dx = 0; dx < 3; ++dx) {
          int xc = xx + dx - 1;
          if (xc < 0 || xc > 4) continue;
          acc[n] += in[yy * 5 + xc] * w9[dy * 3 + dx];
        }
      }
    }
#pragma unroll
    for (int n = 0; n < 25; ++n) red[(ci * 4 + co) * 25 + n] = acc[n];
  }
  __syncthreads();
  if (tid < 100) {
    int co = tid / 25, m = tid % 25;
    float s = 0.f;
    for (int c = 0; c < 64; ++c) s += red[(c * 4 + co) * 25 + m];
    kk4g[blk * 100 + m * 4 + co] = s + kb[co];
  }
  __syncthreads();

  if ((blk & 7) == 0) {
    conv64core(pool_s, iw, red, tid);
    float* dst = p28g + (size_t)(blk >> 3) * 1792;
    for (int idx = tid; idx < 1600; idx += 256) {
      float s = red[idx] + red[1600 + idx] + red[3200 + idx] + red[4800 + idx];
      dst[(idx / 25) * 28 + idx % 25] = s + ib[idx / 25];
    }
  }
}

// ============================================================================
//                 scan v3 (round-6): bf16 V/attn, vectorized LDS
// ============================================================================

__global__ __launch_bounds__(256) void scan3_kernel(
    const unsigned short* __restrict__ vbg, const float* __restrict__ kk4g,
    const float* __restrict__ p28g, const float* __restrict__ qw,
    const float* __restrict__ qb, float* __restrict__ avgg) {
  const int b = blockIdx.x;
  const int tid = threadIdx.x;
  __shared__ __align__(16) unsigned short v_bf[8 * 64 * 40];
  __shared__ __align__(16) unsigned short attn_bf[25 * 32];
  __shared__ float p_s[64 * 28];
  __shared__ float red[100 * 68];
  __shared__ f32x4 kk4_s[8 * 25];
  __shared__ float q_s[100];
  __shared__ float qw_s[2304];
  __shared__ float avgp[256];
  __shared__ float qb_s[4];

  {
    const u32x4* vs = (const u32x4*)(vbg + (size_t)b * 20480);
    u32x4* vd = (u32x4*)v_bf;
    for (int i = tid; i < 2560; i += 256) vd[i] = vs[i];
    const f32x4* ks = (const f32x4*)(kk4g + b * 800);
    for (int i = tid; i < 200; i += 256) kk4_s[i] = ks[i];
    const f32x4* ps = (const f32x4*)(p28g + (size_t)b * 1792);
    f32x4* pd = (f32x4*)p_s;
    for (int i = tid; i < 448; i += 256) pd[i] = ps[i];
    const f32x4* qs = (const f32x4*)qw;
    f32x4* qd = (f32x4*)qw_s;
    for (int i = tid; i < 576; i += 256) qd[i] = qs[i];
    if (tid < 4) qb_s[tid] = qb[tid];
  }
  __syncthreads();

  const int qco = tid & 3, qci = tid >> 2;
  float qwr[9];
#pragma unroll
  for (int tp = 0; tp < 9; ++tp) qwr[tp] = qw_s[(qco * 64 + qci) * 9 + tp];

#pragma unroll 1
  for (int l = 0; l < 8; ++l) {
    {
      f32x4 i4[7];
      const f32x4* pr = (const f32x4*)&p_s[qci * 28];
#pragma unroll
      for (int j = 0; j < 7; ++j) i4[j] = pr[j];
      float in[25];
#pragma unroll
      for (int n = 0; n < 25; ++n) in[n] = i4[n >> 2][n & 3];
      float acc[25];
#pragma unroll
      for (int n = 0; n < 25; ++n) acc[n] = 0.f;
#pragma unroll
      for (int n = 0; n < 25; ++n) {
        int y = n / 5, xx = n % 5;
#pragma unroll
        for (int dy = 0; dy < 3; ++dy) {
          int yy = y + dy - 1;
          if (yy < 0 || yy > 4) continue;
#pragma unroll
          for (int dx = 0; dx < 3; ++dx) {
            int xc = xx + dx - 1;
            if (xc < 0 || xc > 4) continue;
            acc[n] += in[yy * 5 + xc] * qwr[dy * 3 + dx];
          }
        }
      }
#pragma unroll
      for (int n = 0; n < 25; ++n) red[(qco * 25 + n) * 68 + qci] = acc[n];
    }
    if (l > 0 && tid < 64) {
      f32x4 a4 = *(const f32x4*)&avgp[tid * 4];
      avgg[(b * 8 + l - 1) * 64 + tid] = (a4[0] + a4[1] + a4[2] + a4[3]) * 0.04f;
    }
    __syncthreads();

    if (tid < 200) {
      int row = tid >> 1, h = tid & 1;
      const f32x4* rp = (const f32x4*)&red[row * 68 + h * 32];
      float s = 0.f;
#pragma unroll
      for (int j = 0; j < 8; ++j) {
        f32x4 r4 = rp[j];
        s += r4[0] + r4[1] + r4[2] + r4[3];
      }
      s += __shfl_down(s, 1);
      if (h == 0) q_s[row] = s + qb_s[row / 25];
    }
    __syncthreads();

    if (tid < 25) {
      const int n = tid;
      const f32x4* kk = &kk4_s[l * 25];
      float q0 = q_s[n], q1 = q_s[25 + n], q2 = q_s[50 + n], q3 = q_s[75 + n];
      float row[25];
      float mx = -1e30f;
#pragma unroll
      for (int m = 0; m < 25; ++m) {
        f32x4 k4 = kk[m];
        float s = q0 * k4[0] + q1 * k4[1] + q2 * k4[2] + q3 * k4[3];
        row[m] = s;
        mx = fmaxf(mx, s);
      }
      float sm = 0.f;
#pragma unroll
      for (int m = 0; m < 25; ++m) {
        float e = __expf(row[m] - mx);
        row[m] = e;
        sm += e;
      }
      float inv = 1.0f / sm;
      unsigned int w16[16];
#pragma unroll
      for (int j = 0; j < 16; ++j) {
        float lo = (2 * j < 25) ? row[2 * j] * inv : 0.f;
        float hi = (2 * j + 1 < 25) ? row[2 * j + 1] * inv : 0.f;
        w16[j] = (unsigned)bf16r(lo) | ((unsigned)bf16r(hi) << 16);
      }
      u32x4* ad = (u32x4*)&attn_bf[n * 32];
      u32x4 d0 = {w16[0], w16[1], w16[2], w16[3]};
      u32x4 d1 = {w16[4], w16[5], w16[6], w16[7]};
      u32x4 d2 = {w16[8], w16[9], w16[10], w16[11]};
      u32x4 d3 = {w16[12], w16[13], w16[14], w16[15]};
      ad[0] = d0; ad[1] = d1; ad[2] = d2; ad[3] = d3;
    }
    __syncthreads();

    {
      const int c = tid & 63, grp = tid >> 6;
      const u32x4* vr = (const u32x4*)&v_bf[(l * 64 + c) * 40];
      u32x4 vv[4];
#pragma unroll
      for (int j = 0; j < 4; ++j) vv[j] = vr[j];
      float vf[25];
#pragma unroll
      for (int m = 0; m < 25; ++m) {
        unsigned int u = vv[m >> 3][(m >> 1) & 3];
        vf[m] = (m & 1) ? bf_hi(u) : bf_lo(u);
      }
      float partial = 0.f;
      for (int n = grp; n < 25; n += 4) {
        const u32x4* ar = (const u32x4*)&attn_bf[n * 32];
        u32x4 aa[4];
#pragma unroll
        for (int j = 0; j < 4; ++j) aa[j] = ar[j];
        float acc = 0.f;
#pragma unroll
        for (int m = 0; m < 25; ++m) {
          unsigned int u = aa[m >> 3][(m >> 1) & 3];
          float a = (m & 1) ? bf_hi(u) : bf_lo(u);
          acc += vf[m] * a;
        }
        p_s[c * 28 + n] = acc;
        partial += acc;
      }
      avgp[(c << 2) + grp] = partial;
    }
    __syncthreads();
  }
  if (tid < 64) {
    f32x4 a4 = *(const f32x4*)&avgp[tid * 4];
    avgg[(b * 8 + 7) * 64 + tid] = (a4[0] + a4[1] + a4[2] + a4[3]) * 0.04f;
  }
}

// ============================================================================
//                       LEGACY PATH — fallback only
// ============================================================================

__global__ __launch_bounds__(256) void pool_kernel(const float* __restrict__ x,
                                                   float* __restrict__ pooled) {
  const int blk = blockIdx.x;
  const float* plane = x + (size_t)blk * 2500;
  __shared__ float pmax[250];
  const int t = threadIdx.x;
  if (t < 250) {
    int r = t / 5, cc = t % 5;
    const float* row = plane + r * 50 + cc * 10;
    float m = row[0];
#pragma unroll
    for (int j = 1; j < 10; ++j) m = fmaxf(m, row[j]);
    pmax[r * 5 + cc] = m;
  }
  __syncthreads();
  if (t < 25) {
    int pr = t / 5, cc = t % 5;
    float m = pmax[(pr * 10) * 5 + cc];
#pragma unroll
    for (int rr = 1; rr < 10; ++rr) m = fmaxf(m, pmax[(pr * 10 + rr) * 5 + cc]);
    pooled[(size_t)blk * 25 + t] = m;
  }
}

__global__ __launch_bounds__(256) void wt_kernel(const float* __restrict__ w,
                                                 unsigned short* __restrict__ wt2) {
  int idx = blockIdx.x * 256 + threadIdx.x;
  if (idx >= 36864) return;
  int j = idx & 7;
  int lane = (idx >> 3) & 63;
  int mf = (idx >> 9) & 3;
  int ik = (idx >> 11) & 1;
  int tap = idx >> 12;
  int o = mf * 16 + (lane & 15);
  int i = ik * 32 + 8 * (lane >> 4) + j;
  wt2[idx] = bf16r(w[((o * 64) + i) * 9 + tap]);
}

__global__ __launch_bounds__(256) void conv_main(
    const float* __restrict__ x, const unsigned short* __restrict__ wt2,
    const float* __restrict__ scale_g, const float* __restrict__ fb_g,
    float* __restrict__ out) {
  const int g = blockIdx.x & 127;
  const int band = blockIdx.x >> 7;
  const int y0 = band * 4;
  const int tid = threadIdx.x;
  __shared__ unsigned short in_s[6 * 66 * 64];
  __shared__ float scale_s[64], fb_s[64];
  if (tid < 64) {
    scale_s[tid] = scale_g[g * 64 + tid];
    fb_s[tid] = fb_g[g * 64 + tid];
  }
  __syncthreads();
  const float* xg = x + (size_t)g * 160000;
  for (int task = tid; task < 3168; task += 256) {
    int c = task % 66;
    int rc = task / 66;
    int r = rc >> 3;
    int chunk = rc & 7;
    int y = y0 - 1 + r;
    int xi = c - 1;
    unsigned int p0 = 0, p1 = 0, p2 = 0, p3 = 0;
    if (y >= 0 && y < 50 && xi >= 0 && xi < 50) {
      const float* px = xg + chunk * 8 * 2500 + y * 50 + xi;
      float f0 = px[0] * scale_s[chunk * 8 + 0];
      float f1 = px[2500] * scale_s[chunk * 8 + 1];
      float f2 = px[5000] * scale_s[chunk * 8 + 2];
      float f3 = px[7500] * scale_s[chunk * 8 + 3];
      float f4 = px[10000] * scale_s[chunk * 8 + 4];
      float f5 = px[12500] * scale_s[chunk * 8 + 5];
      float f6 = px[15000] * scale_s[chunk * 8 + 6];
      float f7 = px[17500] * scale_s[chunk * 8 + 7];
      p0 = (unsigned)bf16r(f0) | ((unsigned)bf16r(f1) << 16);
      p1 = (unsigned)bf16r(f2) | ((unsigned)bf16r(f3) << 16);
      p2 = (unsigned)bf16r(f4) | ((unsigned)bf16r(f5) << 16);
      p3 = (unsigned)bf16r(f6) | ((unsigned)bf16r(f7) << 16);
    }
    int chS = chunk ^ (c & 7);
    uint4* dst = (uint4*)&in_s[((r * 66 + c) << 6) + (chS << 3)];
    uint4 u4;
    u4.x = p0; u4.y = p1; u4.z = p2; u4.w = p3;
    *dst = u4;
  }
  __syncthreads();
  const int wave = tid >> 6, lane = tid & 63;
  const int l15 = lane & 15, l4 = lane >> 4;
  const int yrow = y0 + wave;
  if (yrow < 50) {
    f32x4 acc[4][4];
    f32x4 z = {0.f, 0.f, 0.f, 0.f};
#pragma unroll
    for (int mf = 0; mf < 4; ++mf)
#pragma unroll
      for (int nf = 0; nf < 4; ++nf) acc[mf][nf] = z;
#pragma unroll
    for (int dy = 0; dy < 3; ++dy) {
      const int rr = wave + dy;
#pragma unroll
      for (int dx = 0; dx < 3; ++dx) {
        const int tap = dy * 3 + dx;
#pragma unroll
        for (int ik = 0; ik < 2; ++ik) {
          s16x8 a[4], bfr[4];
#pragma unroll
          for (int mf = 0; mf < 4; ++mf)
            a[mf] = *reinterpret_cast<const s16x8*>(
                wt2 + ((((tap * 2 + ik) * 4 + mf) * 64 + lane) << 3));
#pragma unroll
          for (int nf = 0; nf < 4; ++nf) {
            int cc = nf * 16 + l15 + dx;
            int chS = (ik * 4 + l4) ^ (cc & 7);
            bfr[nf] = *reinterpret_cast<const s16x8*>(
                &in_s[((rr * 66 + cc) << 6) + (chS << 3)]);
          }
#pragma unroll
          for (int mf = 0; mf < 4; ++mf)
#pragma unroll
            for (int nf = 0; nf < 4; ++nf)
              acc[mf][nf] = __builtin_amdgcn_mfma_f32_16x16x32_bf16(
                  a[mf], bfr[nf], acc[mf][nf], 0, 0, 0);
        }
      }
    }
    float* og = out + (size_t)g * 64 * 2500 + yrow * 50;
#pragma unroll
    for (int mf = 0; mf < 4; ++mf) {
#pragma unroll
      for (int r = 0; r < 4; ++r) {
        int o = mf * 16 + l4 * 4 + r;
        float fbv = fb_s[o];
#pragma unroll
        for (int nf = 0; nf < 4; ++nf) {
          int xx = nf * 16 + l15;
          if (xx < 50) og[(size_t)o * 2500 + xx] = acc[mf][nf][r] + fbv;
        }
      }
    }
  }
}

__global__ __launch_bounds__(256) void calib_kernel(
    const float* __restrict__ avgg, const float* __restrict__ tconvw,
    const float* __restrict__ tconvb, const float* __restrict__ fcw,
    const float* __restrict__ fcb, const float* __restrict__ bias,
    float* __restrict__ scale_g, float* __restrict__ fb_g) {
  const int tid = threadIdx.x;
  const int wave = tid >> 6, o = tid & 63;
  const int bl = blockIdx.x * 4 + wave;
  __shared__ float tcw_s[64 * 65];
  __shared__ float avgl[4][64];
  for (int idx = tid; idx < 4096; idx += 256)
    tcw_s[(idx >> 6) * 65 + (idx & 63)] = tconvw[idx];
  avgl[wave][o] = avgg[bl * 64 + o];
  __syncthreads();
  float cal = tconvb[o];
  const float* av = avgl[wave];
#pragma unroll
  for (int c = 0; c < 64; ++c) cal += tcw_s[o * 65 + c] * av[c];
  scale_g[bl * 64 + o] = 1.0f + cal;
  float part = fcw[o] * av[o];
#pragma unroll
  for (int off = 32; off; off >>= 1) part += __shfl_down(part, off);
  float fc = __shfl(part, 0) + fcb[0];
  fb_g[bl * 64 + o] = bias[o] * (1.0f + fc);
}

// --------------------------------- launch ---------------------------------
extern "C" void kernel_launch(void* const* d_in, const int* in_sizes, int n_in,
                              void* d_out, int out_size, void* d_ws, size_t ws_size,
                              hipStream_t stream) {
  const float* x       = (const float*)d_in[0];
  const float* weight  = (const float*)d_in[1];
  const float* bias    = (const float*)d_in[2];
  const float* init_w  = (const float*)d_in[3];
  const float* init_b  = (const float*)d_in[4];
  const float* q_w     = (const float*)d_in[5];
  const float* q_b     = (const float*)d_in[6];
  const float* k_w     = (const float*)d_in[7];
  const float* k_b     = (const float*)d_in[8];
  const float* v_w     = (const float*)d_in[9];
  const float* v_b     = (const float*)d_in[10];
  const float* tconv_w = (const float*)d_in[11];
  const float* tconv_b = (const float*)d_in[12];
  const float* fc_w    = (const float*)d_in[13];
  const float* fc_b    = (const float*)d_in[14];
  float* out = (float*)d_out;

  float* ws = (float*)d_ws;
  float* pooled = ws;                                      // 204800 f
  unsigned short* vbg = (unsigned short*)(ws + 204800);    // 327680 us
  float* kk4g   = ws + 368640;                             // 12800 f
  float* p28g   = ws + 381440;                             // 28672 f
  float* scaleg = ws + 410112;                             // 8192 f (legacy)
  float* fbg    = ws + 418304;                             // 8192 f
  float* avgg   = ws + 426496;                             // 8192 f
  unsigned short* wt3 = (unsigned short*)(ws + 434688);    // 4718592 us
  unsigned short* xsb = wt3 + 4718592;                     // 22151168 us

  const size_t NEED_FAST = 55543808ull;

  if (ws_size >= NEED_FAST) {
    poolprep2_kernel<<<1280, 256, 0, stream>>>(x, pooled, xsb);
    convB2_kernel<<<128, 256, 0, stream>>>(pooled, v_w, v_b, k_w, k_b, init_w,
                                           init_b, vbg, kk4g, p28g);
    scan3_kernel<<<16, 256, 0, stream>>>(vbg, kk4g, p28g, q_w, q_b, avgg);
    calwt_kernel<<<128, 256, 0, stream>>>(avgg, tconv_w, tconv_b, fc_w, fc_b, bias,
                                          weight, fbg, wt3);
    conv_main_fast2<<<13 * 128, 256, 0, stream>>>(xsb, wt3, fbg, out);
  } else {
    unsigned short* wt2 = (unsigned short*)(ws + 434688);
    pool_kernel<<<8192, 256, 0, stream>>>(x, pooled);
    wt_kernel<<<144, 256, 0, stream>>>(weight, wt2);
    convB2_kernel<<<128, 256, 0, stream>>>(pooled, v_w, v_b, k_w, k_b, init_w,
                                           init_b, vbg, kk4g, p28g);
    scan3_kernel<<<16, 256, 0, stream>>>(vbg, kk4g, p28g, q_w, q_b, avgg);
    calib_kernel<<<32, 256, 0, stream>>>(avgg, tconv_w, tconv_b, fc_w, fc_b, bias,
                                         scaleg, fbg);
    conv_main<<<13 * 128, 256, 0, stream>>>(x, wt2, scaleg, fbg, out);
  }
}